// Round 5
// baseline (82.771 us; speedup 1.0000x reference)
//
#include <hip/hip_runtime.h>

#define QTOT 12240
#define KD   256

typedef float f32x4 __attribute__((ext_vector_type(4)));
typedef short s16x8 __attribute__((ext_vector_type(8)));
typedef unsigned short ushort_t;

__device__ __forceinline__ unsigned short f2b(float x) {
    union { float f; unsigned u; } c; c.f = x;
    unsigned r = c.u + 0x7fffu + ((c.u >> 16) & 1u);
    return (unsigned short)(r >> 16);
}
// full-K LDS row: 512B, XOR bits 4-6 of k-byte with row&7 (both write & read sides)
__device__ __forceinline__ int swz(int row, int kb) { return row * 512 + (kb ^ ((row & 7) << 4)); }

// ---------------------------------------------------------------------------
// prep: weight transpose+bf16, combined off/attn bias (unchanged from r4)
// ---------------------------------------------------------------------------
__global__ __launch_bounds__(256) void prep(
    const float* __restrict__ W_val, const float* __restrict__ W_off,
    const float* __restrict__ W_attn, const float* __restrict__ W_out,
    const float* __restrict__ b_off, const float* __restrict__ b_attn,
    ushort_t* __restrict__ WvT, ushort_t* __restrict__ WcT,
    ushort_t* __restrict__ WoT, float* __restrict__ bcomb)
{
    int id = blockIdx.x * 256 + threadIdx.x;
    if (id < 65536) { int n = id >> 8, k = id & 255; WvT[id] = f2b(W_val[k * 256 + n]); }
    else if (id < 163840) {
        int t = id - 65536; int n = t >> 8, k = t & 255;
        float v = (n < 256) ? W_off[k * 256 + n] : W_attn[k * 128 + (n - 256)];
        WcT[t] = f2b(v);
    } else if (id < 229376) {
        int t = id - 163840; int n = t >> 8, k = t & 255;
        WoT[t] = f2b(W_out[k * 256 + n]);
    } else if (id < 229760) {
        int t = id - 229376; bcomb[t] = (t < 256) ? b_off[t] : b_attn[t - 256];
    }
}

// ---------------------------------------------------------------------------
// Stage full-K B panel (64 n-rows x 256 k) bf16 from WT[n][k] into swizzled LDS.
// ---------------------------------------------------------------------------
__device__ __forceinline__ void stageB_full(const ushort_t* __restrict__ WT, int bn, char* Bs) {
    const int t = threadIdx.x;
    const int n = t >> 2, c0 = (t & 3) * 64;
    const ushort_t* src = WT + (size_t)(bn + n) * KD + c0;
#pragma unroll
    for (int j = 0; j < 8; ++j)
        *(s16x8*)(Bs + swz(n, (c0 + j * 8) * 2)) = *(const s16x8*)(src + j * 8);
}

// ---------------------------------------------------------------------------
// Barrier-free MFMA sweep: both panels resident, 8 k-chunks, 2x2 frags/wave.
// ---------------------------------------------------------------------------
__device__ __forceinline__ void mm64(char* As, char* Bs, f32x4 (&acc)[2][2]) {
    const int tid = threadIdx.x, lane = tid & 63, wave = tid >> 6;
    const int wr = wave >> 1, wc = wave & 1;
    const int lr = lane & 15, g8 = (lane >> 4) * 8;
#pragma unroll
    for (int kc = 0; kc < 8; ++kc) {
        const int kb = (kc * 32 + g8) * 2;
        s16x8 a0 = *(const s16x8*)(As + swz(wr * 32 + lr,      kb));
        s16x8 a1 = *(const s16x8*)(As + swz(wr * 32 + 16 + lr, kb));
        s16x8 b0 = *(const s16x8*)(Bs + swz(wc * 32 + lr,      kb));
        s16x8 b1 = *(const s16x8*)(Bs + swz(wc * 32 + 16 + lr, kb));
        acc[0][0] = __builtin_amdgcn_mfma_f32_16x16x32_bf16(a0, b0, acc[0][0], 0, 0, 0);
        acc[0][1] = __builtin_amdgcn_mfma_f32_16x16x32_bf16(a0, b1, acc[0][1], 0, 0, 0);
        acc[1][0] = __builtin_amdgcn_mfma_f32_16x16x32_bf16(a1, b0, acc[1][0], 0, 0, 0);
        acc[1][1] = __builtin_amdgcn_mfma_f32_16x16x32_bf16(a1, b1, acc[1][1], 0, 0, 0);
    }
}

// ---------------------------------------------------------------------------
// gemm1: grid 1920 = 192 m-tiles x 10 n-tiles (0-3 value proj, 4-9 off/attn).
// XCD swizzle keeps one m-tile's n-tiles on one XCD (A re-reads hit L2).
// ---------------------------------------------------------------------------
__global__ __launch_bounds__(256) void gemm1(
    const float* __restrict__ inflat, const float* __restrict__ query,
    const ushort_t* __restrict__ WvT, const ushort_t* __restrict__ WcT,
    const float* __restrict__ b_val, const float* __restrict__ bcomb,
    ushort_t* __restrict__ projb, ushort_t* __restrict__ offb,
    float* __restrict__ logitf)
{
    __shared__ char As[32768];
    __shared__ char Bs[32768];
    const int bid = blockIdx.x;
    const int linear = (bid & 7) * 240 + (bid >> 3);
    const int mt = linear / 10, nt = linear - mt * 10;
    const int bm = mt * 64;
    const bool isval = nt < 4;
    const int bnc = isval ? nt * 64 : (nt - 4) * 64;   // col base in output space

    if (isval) stageB_full(WvT, bnc, Bs);
    else       stageB_full(WcT, bnc, Bs);

    {   // stage A panel: 64 rows x 256 k, f32 -> bf16, once
        const int t = threadIdx.x;
        const int row = t >> 2, c0 = (t & 3) * 64;
        const int grow = bm + row;
        const float* A = isval ? inflat : query;
        float4 f[16];
        if (grow < QTOT) {
            const float4* s = (const float4*)(A + (size_t)grow * KD + c0);
#pragma unroll
            for (int i = 0; i < 16; ++i) f[i] = s[i];
        } else {
#pragma unroll
            for (int i = 0; i < 16; ++i) f[i] = make_float4(0.f, 0.f, 0.f, 0.f);
        }
#pragma unroll
        for (int j = 0; j < 8; ++j) {
            s16x8 v;
            v[0] = f2b(f[2*j].x);   v[1] = f2b(f[2*j].y);
            v[2] = f2b(f[2*j].z);   v[3] = f2b(f[2*j].w);
            v[4] = f2b(f[2*j+1].x); v[5] = f2b(f[2*j+1].y);
            v[6] = f2b(f[2*j+1].z); v[7] = f2b(f[2*j+1].w);
            *(s16x8*)(As + swz(row, (c0 + j * 8) * 2)) = v;
        }
    }
    __syncthreads();

    f32x4 acc[2][2];
#pragma unroll
    for (int m = 0; m < 2; ++m)
#pragma unroll
        for (int n = 0; n < 2; ++n) acc[m][n] = (f32x4)0.f;
    mm64(As, Bs, acc);

    const int lane = threadIdx.x & 63, wave = threadIdx.x >> 6;
    const int wr = wave >> 1, wc = wave & 1;
    const int lr = lane & 15, rg = (lane >> 4) * 4;
#pragma unroll
    for (int n = 0; n < 2; ++n) {
        const int col = bnc + wc * 32 + n * 16 + lr;
        const float bb = isval ? b_val[col] : bcomb[col];
#pragma unroll
        for (int m = 0; m < 2; ++m)
#pragma unroll
            for (int rr = 0; rr < 4; ++rr) {
                const int row = bm + wr * 32 + m * 16 + rg + rr;
                if (row >= QTOT) continue;
                const float v = acc[m][n][rr] + bb;
                if (isval)          projb[(size_t)row * 256 + col] = f2b(v);
                else if (col < 256) offb [(size_t)row * 256 + col] = f2b(v);
                else                logitf[(size_t)row * 128 + col - 256] = v;
            }
    }
}

// ---------------------------------------------------------------------------
// gemm_o: grid 768 = 192 m-tiles x 4 n-tiles; A = outpre bf16.
// ---------------------------------------------------------------------------
__global__ __launch_bounds__(256) void gemm_o(
    const ushort_t* __restrict__ Ab, const ushort_t* __restrict__ WoT,
    const float* __restrict__ b_out, float* __restrict__ out)
{
    __shared__ char As[32768];
    __shared__ char Bs[32768];
    const int bid = blockIdx.x;
    const int linear = (bid & 7) * 96 + (bid >> 3);
    const int mt = linear >> 2, nt = linear & 3;
    const int bm = mt * 64;

    stageB_full(WoT, nt * 64, Bs);

    {   // stage A panel bf16
        const int t = threadIdx.x;
        const int row = t >> 2, c0 = (t & 3) * 64;
        const int grow = bm + row;
        if (grow < QTOT) {
            const ushort_t* s = Ab + (size_t)grow * KD + c0;
#pragma unroll
            for (int j = 0; j < 8; ++j)
                *(s16x8*)(As + swz(row, (c0 + j * 8) * 2)) = *(const s16x8*)(s + j * 8);
        } else {
            s16x8 z = (s16x8)0;
#pragma unroll
            for (int j = 0; j < 8; ++j)
                *(s16x8*)(As + swz(row, (c0 + j * 8) * 2)) = z;
        }
    }
    __syncthreads();

    f32x4 acc[2][2];
#pragma unroll
    for (int m = 0; m < 2; ++m)
#pragma unroll
        for (int n = 0; n < 2; ++n) acc[m][n] = (f32x4)0.f;
    mm64(As, Bs, acc);

    const int lane = threadIdx.x & 63, wave = threadIdx.x >> 6;
    const int wr = wave >> 1, wc = wave & 1;
    const int lr = lane & 15, rg = (lane >> 4) * 4;
#pragma unroll
    for (int n = 0; n < 2; ++n) {
        const int col = nt * 64 + wc * 32 + n * 16 + lr;
        const float bb = b_out[col];
#pragma unroll
        for (int m = 0; m < 2; ++m)
#pragma unroll
            for (int rr = 0; rr < 4; ++rr) {
                const int row = bm + wr * 32 + m * 16 + rg + rr;
                if (row < QTOT) out[(size_t)row * 256 + col] = acc[m][n][rr] + bb;
            }
    }
}

// ---------------------------------------------------------------------------
// sample: unchanged from r4 (2 queries/block, dwordx4 gathers, XCD swizzle)
// ---------------------------------------------------------------------------
__global__ __launch_bounds__(256) void sample4(
    const float* __restrict__ rp, const ushort_t* __restrict__ offb,
    const float* __restrict__ logitf, const ushort_t* __restrict__ projb,
    const int* __restrict__ sp, const int* __restrict__ lsi,
    ushort_t* __restrict__ outpre)
{
    const int bid = blockIdx.x;
    const int qpair = (bid & 7) * 765 + (bid >> 3);     // 6120 = 8*765 bijective
    const int tid = threadIdx.x;
    const int qi = tid >> 7;
    const int q = qpair * 2 + qi;

    __shared__ int   s_idx[256][4];
    __shared__ float s_w[256][4];

    {
        const int t = tid & 127;
        const int l = (t >> 2) & 3;
        float logit = logitf[(size_t)q * 128 + t];
        float mx = logit;
#pragma unroll
        for (int d = 1; d < 16; d <<= 1) mx = fmaxf(mx, __shfl_xor(mx, d));
        float e = __expf(logit - mx);
        float s = e;
#pragma unroll
        for (int d = 1; d < 16; d <<= 1) s += __shfl_xor(s, d);
        const float aw = e / s;

        const unsigned opk = *(const unsigned*)&offb[(size_t)q * 256 + t * 2];
        const float ox = __uint_as_float(opk << 16);
        const float oy = __uint_as_float(opk & 0xffff0000u);

        const int Hl = sp[l * 2], Wl = sp[l * 2 + 1], st = lsi[l];
        const float rx = rp[((size_t)q * 4 + l) * 2 + 0];
        const float ry = rp[((size_t)q * 4 + l) * 2 + 1];

        const float x = rx * (float)Wl + ox - 0.5f;
        const float y = ry * (float)Hl + oy - 0.5f;
        const float xf = floorf(x), yf = floorf(y);
        const int x0 = (int)xf, y0 = (int)yf;
        const float lx = x - xf, ly = y - yf;

        const bool vx0 = (x0 >= 0) && (x0 < Wl);
        const bool vx1 = (x0 + 1 >= 0) && (x0 + 1 < Wl);
        const bool vy0 = (y0 >= 0) && (y0 < Hl);
        const bool vy1 = (y0 + 1 >= 0) && (y0 + 1 < Hl);

        s_w[tid][0] = (vx0 && vy0) ? aw * (1.f - ly) * (1.f - lx) : 0.f;
        s_w[tid][1] = (vx1 && vy0) ? aw * (1.f - ly) * lx         : 0.f;
        s_w[tid][2] = (vx0 && vy1) ? aw * ly * (1.f - lx)         : 0.f;
        s_w[tid][3] = (vx1 && vy1) ? aw * ly * lx                 : 0.f;
        s_idx[tid][0] = (vx0 && vy0) ? (st + y0 * Wl + x0) * 512           : 0;
        s_idx[tid][1] = (vx1 && vy0) ? (st + y0 * Wl + x0 + 1) * 512       : 0;
        s_idx[tid][2] = (vx0 && vy1) ? (st + (y0 + 1) * Wl + x0) * 512     : 0;
        s_idx[tid][3] = (vx1 && vy1) ? (st + (y0 + 1) * Wl + x0 + 1) * 512 : 0;
    }
    __syncthreads();

    const int tt = tid & 127;
    const int h = tt >> 4, qtr = (tt >> 2) & 3, c8 = tt & 3;
    const char* basec = (const char*)projb + (h * 32 + c8 * 8) * 2;

    float a0 = 0, a1 = 0, a2 = 0, a3 = 0, a4 = 0, a5 = 0, a6 = 0, a7 = 0;
#pragma unroll
    for (int p = 0; p < 4; ++p) {
        const int slot = qi * 128 + h * 16 + qtr * 4 + p;
        const int4   id4 = *(const int4*)s_idx[slot];
        const float4 w4  = *(const float4*)s_w[slot];
#pragma unroll
        for (int c = 0; c < 4; ++c) {
            const int   id = (c == 0) ? id4.x : (c == 1) ? id4.y : (c == 2) ? id4.z : id4.w;
            const float w  = (c == 0) ? w4.x  : (c == 1) ? w4.y  : (c == 2) ? w4.z  : w4.w;
            const uint4 v = *(const uint4*)(basec + id);
            a0 += w * __uint_as_float(v.x << 16);
            a1 += w * __uint_as_float(v.x & 0xffff0000u);
            a2 += w * __uint_as_float(v.y << 16);
            a3 += w * __uint_as_float(v.y & 0xffff0000u);
            a4 += w * __uint_as_float(v.z << 16);
            a5 += w * __uint_as_float(v.z & 0xffff0000u);
            a6 += w * __uint_as_float(v.w << 16);
            a7 += w * __uint_as_float(v.w & 0xffff0000u);
        }
    }
    a0 += __shfl_xor(a0, 4); a1 += __shfl_xor(a1, 4);
    a2 += __shfl_xor(a2, 4); a3 += __shfl_xor(a3, 4);
    a4 += __shfl_xor(a4, 4); a5 += __shfl_xor(a5, 4);
    a6 += __shfl_xor(a6, 4); a7 += __shfl_xor(a7, 4);
    a0 += __shfl_xor(a0, 8); a1 += __shfl_xor(a1, 8);
    a2 += __shfl_xor(a2, 8); a3 += __shfl_xor(a3, 8);
    a4 += __shfl_xor(a4, 8); a5 += __shfl_xor(a5, 8);
    a6 += __shfl_xor(a6, 8); a7 += __shfl_xor(a7, 8);

    if (qtr == 0) {
        uint4 o;
        o.x = (unsigned)f2b(a0) | ((unsigned)f2b(a1) << 16);
        o.y = (unsigned)f2b(a2) | ((unsigned)f2b(a3) << 16);
        o.z = (unsigned)f2b(a4) | ((unsigned)f2b(a5) << 16);
        o.w = (unsigned)f2b(a6) | ((unsigned)f2b(a7) << 16);
        *(uint4*)&outpre[(size_t)q * 256 + h * 32 + c8 * 8] = o;
    }
}

// ---------------------------------------------------------------------------
extern "C" void kernel_launch(void* const* d_in, const int* in_sizes, int n_in,
                              void* d_out, int out_size, void* d_ws, size_t ws_size,
                              hipStream_t stream) {
    const float* query  = (const float*)d_in[0];
    const float* rp     = (const float*)d_in[1];
    const float* inflat = (const float*)d_in[2];
    const int*   sp     = (const int*)d_in[3];
    const int*   lsi    = (const int*)d_in[4];
    const float* W_off  = (const float*)d_in[5];
    const float* b_off  = (const float*)d_in[6];
    const float* W_attn = (const float*)d_in[7];
    const float* b_attn = (const float*)d_in[8];
    const float* W_val  = (const float*)d_in[9];
    const float* b_val  = (const float*)d_in[10];
    const float* W_out  = (const float*)d_in[11];
    const float* b_out  = (const float*)d_in[12];
    float* out = (float*)d_out;

    char* ws = (char*)d_ws;
    ushort_t* projb  = (ushort_t*)ws; ws += (size_t)QTOT * 256 * 2;
    ushort_t* offb   = (ushort_t*)ws; ws += (size_t)QTOT * 256 * 2;
    float*    logitf = (float*)ws;    ws += (size_t)QTOT * 128 * 4;
    ushort_t* outpre = (ushort_t*)ws; ws += (size_t)QTOT * 256 * 2;
    ushort_t* WvT    = (ushort_t*)ws; ws += 65536 * 2;
    ushort_t* WcT    = (ushort_t*)ws; ws += 98304 * 2;
    ushort_t* WoT    = (ushort_t*)ws; ws += 65536 * 2;
    float*    bcomb  = (float*)ws;    ws += 384 * 4;

    dim3 blk(256);

    prep<<<dim3(898), blk, 0, stream>>>(W_val, W_off, W_attn, W_out, b_off, b_attn,
                                        WvT, WcT, WoT, bcomb);

    gemm1<<<dim3(1920), blk, 0, stream>>>(inflat, query, WvT, WcT, b_val, bcomb,
                                          projb, offb, logitf);

    sample4<<<dim3(6120), blk, 0, stream>>>(rp, offb, logitf, projb, sp, lsi, outpre);

    gemm_o<<<dim3(768), blk, 0, stream>>>(outpre, WoT, b_out, out);
}

// Round 6
// 81.883 us; speedup vs baseline: 1.0108x; 1.0108x over previous
//
#include <hip/hip_runtime.h>

#define QTOT 12240
#define KD   256

typedef float f32x4 __attribute__((ext_vector_type(4)));
typedef short s16x8 __attribute__((ext_vector_type(8)));
typedef unsigned short ushort_t;

__device__ __forceinline__ unsigned short f2b(float x) {
    union { float f; unsigned u; } c; c.f = x;
    unsigned r = c.u + 0x7fffu + ((c.u >> 16) & 1u);
    return (unsigned short)(r >> 16);
}
// full-K LDS row: 512B, XOR bits 4-6 of k-byte with row&7 (write & read sides)
__device__ __forceinline__ int swz(int row, int kb) { return row * 512 + (kb ^ ((row & 7) << 4)); }

// ---------------------------------------------------------------------------
// prep: weight transpose+bf16, combined off/attn bias
// ---------------------------------------------------------------------------
__global__ __launch_bounds__(256) void prep(
    const float* __restrict__ W_val, const float* __restrict__ W_off,
    const float* __restrict__ W_attn, const float* __restrict__ W_out,
    const float* __restrict__ b_off, const float* __restrict__ b_attn,
    ushort_t* __restrict__ WvT, ushort_t* __restrict__ WcT,
    ushort_t* __restrict__ WoT, float* __restrict__ bcomb)
{
    int id = blockIdx.x * 256 + threadIdx.x;
    if (id < 65536) { int n = id >> 8, k = id & 255; WvT[id] = f2b(W_val[k * 256 + n]); }
    else if (id < 163840) {
        int t = id - 65536; int n = t >> 8, k = t & 255;
        float v = (n < 256) ? W_off[k * 256 + n] : W_attn[k * 128 + (n - 256)];
        WcT[t] = f2b(v);
    } else if (id < 229376) {
        int t = id - 163840; int n = t >> 8, k = t & 255;
        WoT[t] = f2b(W_out[k * 256 + n]);
    } else if (id < 229760) {
        int t = id - 229376; bcomb[t] = (t < 256) ? b_off[t] : b_attn[t - 256];
    }
}

// ---------------------------------------------------------------------------
// gemm1: grid 1920 = 192 m-tiles x 10 n-tiles (0-3 value, 4-9 off/attn).
// A panel (64 x 256) f32->bf16 staged once into swizzled LDS; B held in
// registers per wave (8 x dwordx4, fragment-layout-exact); single barrier.
// XCD swizzle keeps an m-stripe's n-tiles on one XCD (A re-reads L2-hot).
// ---------------------------------------------------------------------------
__global__ __launch_bounds__(256) void gemm1(
    const float* __restrict__ inflat, const float* __restrict__ query,
    const ushort_t* __restrict__ WvT, const ushort_t* __restrict__ WcT,
    const float* __restrict__ b_val, const float* __restrict__ bcomb,
    ushort_t* __restrict__ projb, ushort_t* __restrict__ offb,
    float* __restrict__ logitf)
{
    __shared__ char As[32768];
    const int bid = blockIdx.x;
    const int linear = (bid & 7) * 240 + (bid >> 3);
    const int mt = linear / 10, nt = linear - mt * 10;
    const int bm = mt * 64;
    const bool isval = nt < 4;
    const int bnc = isval ? nt * 64 : (nt - 4) * 64;
    const ushort_t* WT = isval ? WvT : WcT;
    const float* A = isval ? inflat : query;

    const int tid = threadIdx.x, lane = tid & 63, wave = tid >> 6;
    const int lr = lane & 15, g8 = (lane >> 4) * 8;

    // B slice for this wave: cols [bnc+wave*16, +16), full K, fragment layout.
    s16x8 bfr[8];
    {
        const ushort_t* bp = WT + (size_t)(bnc + wave * 16 + lr) * KD + g8;
#pragma unroll
        for (int kc = 0; kc < 8; ++kc) bfr[kc] = *(const s16x8*)(bp + kc * 32);
    }

    {   // stage A panel: 64 rows x 256 k, f32 -> bf16, once
        const int row = tid >> 2, c0 = (tid & 3) * 64;
        const int grow = bm + row;
        if (grow < QTOT) {
            const float4* src = (const float4*)(A + (size_t)grow * KD + c0);
#pragma unroll
            for (int j = 0; j < 4; ++j) {
                float4 f0 = src[j * 4 + 0], f1 = src[j * 4 + 1];
                float4 f2 = src[j * 4 + 2], f3 = src[j * 4 + 3];
                s16x8 v0, v1;
                v0[0] = f2b(f0.x); v0[1] = f2b(f0.y); v0[2] = f2b(f0.z); v0[3] = f2b(f0.w);
                v0[4] = f2b(f1.x); v0[5] = f2b(f1.y); v0[6] = f2b(f1.z); v0[7] = f2b(f1.w);
                v1[0] = f2b(f2.x); v1[1] = f2b(f2.y); v1[2] = f2b(f2.z); v1[3] = f2b(f2.w);
                v1[4] = f2b(f3.x); v1[5] = f2b(f3.y); v1[6] = f2b(f3.z); v1[7] = f2b(f3.w);
                *(s16x8*)(As + swz(row, (c0 + j * 16) * 2))     = v0;
                *(s16x8*)(As + swz(row, (c0 + j * 16 + 8) * 2)) = v1;
            }
        } else {
            s16x8 z = (s16x8)0;
#pragma unroll
            for (int j = 0; j < 8; ++j)
                *(s16x8*)(As + swz(row, (c0 + j * 8) * 2)) = z;
        }
    }
    __syncthreads();

    f32x4 acc[4];
#pragma unroll
    for (int mf = 0; mf < 4; ++mf) acc[mf] = (f32x4)0.f;

#pragma unroll
    for (int kc = 0; kc < 8; ++kc) {
        const int kb = (kc * 32 + g8) * 2;
#pragma unroll
        for (int mf = 0; mf < 4; ++mf) {
            s16x8 af = *(const s16x8*)(As + swz(mf * 16 + lr, kb));
            acc[mf] = __builtin_amdgcn_mfma_f32_16x16x32_bf16(af, bfr[kc], acc[mf], 0, 0, 0);
        }
    }

    const int rg = (lane >> 4) * 4;
    const int col = bnc + wave * 16 + lr;
    const float bb = isval ? b_val[col] : bcomb[col];
#pragma unroll
    for (int mf = 0; mf < 4; ++mf)
#pragma unroll
        for (int rr = 0; rr < 4; ++rr) {
            const int row = bm + mf * 16 + rg + rr;
            if (row >= QTOT) continue;
            const float v = acc[mf][rr] + bb;
            if (isval)          projb[(size_t)row * 256 + col] = f2b(v);
            else if (col < 256) offb [(size_t)row * 256 + col] = f2b(v);
            else                logitf[(size_t)row * 128 + col - 256] = v;
        }
}

// ---------------------------------------------------------------------------
// gemm_o: LDS-free, barrier-free. grid 768 = 192 m-tiles x 4 n-tiles.
// A (bf16) and B fragments loaded directly from global (L1/L2-hot).
// ---------------------------------------------------------------------------
__global__ __launch_bounds__(256) void gemm_o(
    const ushort_t* __restrict__ Ab, const ushort_t* __restrict__ WoT,
    const float* __restrict__ b_out, float* __restrict__ out)
{
    const int bid = blockIdx.x;
    const int linear = (bid & 7) * 96 + (bid >> 3);
    const int mt = linear >> 2, nt = linear & 3;
    const int bm = mt * 64;

    const int tid = threadIdx.x, lane = tid & 63, wave = tid >> 6;
    const int lr = lane & 15, g8 = (lane >> 4) * 8;

    // B slice: cols [nt*64 + wave*16, +16), full K
    s16x8 bfr[8];
    {
        const ushort_t* bp = WoT + (size_t)(nt * 64 + wave * 16 + lr) * KD + g8;
#pragma unroll
        for (int kc = 0; kc < 8; ++kc) bfr[kc] = *(const s16x8*)(bp + kc * 32);
    }

    // A fragment row pointers (clamped; invalid rows not stored)
    const ushort_t* ap[4];
#pragma unroll
    for (int mf = 0; mf < 4; ++mf) {
        int r = bm + mf * 16 + lr;
        if (r >= QTOT) r = QTOT - 1;
        ap[mf] = Ab + (size_t)r * KD + g8;
    }

    f32x4 acc[4];
#pragma unroll
    for (int mf = 0; mf < 4; ++mf) acc[mf] = (f32x4)0.f;

#pragma unroll
    for (int kc = 0; kc < 8; ++kc) {
#pragma unroll
        for (int mf = 0; mf < 4; ++mf) {
            s16x8 af = *(const s16x8*)(ap[mf] + kc * 32);
            acc[mf] = __builtin_amdgcn_mfma_f32_16x16x32_bf16(af, bfr[kc], acc[mf], 0, 0, 0);
        }
    }

    const int rg = (lane >> 4) * 4;
    const int col = nt * 64 + wave * 16 + lr;
    const float bb = b_out[col];
#pragma unroll
    for (int mf = 0; mf < 4; ++mf)
#pragma unroll
        for (int rr = 0; rr < 4; ++rr) {
            const int row = bm + mf * 16 + rg + rr;
            if (row < QTOT) out[(size_t)row * 256 + col] = acc[mf][rr] + bb;
        }
}

// ---------------------------------------------------------------------------
// sample: unchanged from r4 (2 queries/block, dwordx4 gathers, XCD swizzle)
// ---------------------------------------------------------------------------
__global__ __launch_bounds__(256) void sample4(
    const float* __restrict__ rp, const ushort_t* __restrict__ offb,
    const float* __restrict__ logitf, const ushort_t* __restrict__ projb,
    const int* __restrict__ sp, const int* __restrict__ lsi,
    ushort_t* __restrict__ outpre)
{
    const int bid = blockIdx.x;
    const int qpair = (bid & 7) * 765 + (bid >> 3);     // 6120 = 8*765 bijective
    const int tid = threadIdx.x;
    const int qi = tid >> 7;
    const int q = qpair * 2 + qi;

    __shared__ int   s_idx[256][4];
    __shared__ float s_w[256][4];

    {
        const int t = tid & 127;
        const int l = (t >> 2) & 3;
        float logit = logitf[(size_t)q * 128 + t];
        float mx = logit;
#pragma unroll
        for (int d = 1; d < 16; d <<= 1) mx = fmaxf(mx, __shfl_xor(mx, d));
        float e = __expf(logit - mx);
        float s = e;
#pragma unroll
        for (int d = 1; d < 16; d <<= 1) s += __shfl_xor(s, d);
        const float aw = e / s;

        const unsigned opk = *(const unsigned*)&offb[(size_t)q * 256 + t * 2];
        const float ox = __uint_as_float(opk << 16);
        const float oy = __uint_as_float(opk & 0xffff0000u);

        const int Hl = sp[l * 2], Wl = sp[l * 2 + 1], st = lsi[l];
        const float rx = rp[((size_t)q * 4 + l) * 2 + 0];
        const float ry = rp[((size_t)q * 4 + l) * 2 + 1];

        const float x = rx * (float)Wl + ox - 0.5f;
        const float y = ry * (float)Hl + oy - 0.5f;
        const float xf = floorf(x), yf = floorf(y);
        const int x0 = (int)xf, y0 = (int)yf;
        const float lx = x - xf, ly = y - yf;

        const bool vx0 = (x0 >= 0) && (x0 < Wl);
        const bool vx1 = (x0 + 1 >= 0) && (x0 + 1 < Wl);
        const bool vy0 = (y0 >= 0) && (y0 < Hl);
        const bool vy1 = (y0 + 1 >= 0) && (y0 + 1 < Hl);

        s_w[tid][0] = (vx0 && vy0) ? aw * (1.f - ly) * (1.f - lx) : 0.f;
        s_w[tid][1] = (vx1 && vy0) ? aw * (1.f - ly) * lx         : 0.f;
        s_w[tid][2] = (vx0 && vy1) ? aw * ly * (1.f - lx)         : 0.f;
        s_w[tid][3] = (vx1 && vy1) ? aw * ly * lx                 : 0.f;
        s_idx[tid][0] = (vx0 && vy0) ? (st + y0 * Wl + x0) * 512           : 0;
        s_idx[tid][1] = (vx1 && vy0) ? (st + y0 * Wl + x0 + 1) * 512       : 0;
        s_idx[tid][2] = (vx0 && vy1) ? (st + (y0 + 1) * Wl + x0) * 512     : 0;
        s_idx[tid][3] = (vx1 && vy1) ? (st + (y0 + 1) * Wl + x0 + 1) * 512 : 0;
    }
    __syncthreads();

    const int tt = tid & 127;
    const int h = tt >> 4, qtr = (tt >> 2) & 3, c8 = tt & 3;
    const char* basec = (const char*)projb + (h * 32 + c8 * 8) * 2;

    float a0 = 0, a1 = 0, a2 = 0, a3 = 0, a4 = 0, a5 = 0, a6 = 0, a7 = 0;
#pragma unroll
    for (int p = 0; p < 4; ++p) {
        const int slot = qi * 128 + h * 16 + qtr * 4 + p;
        const int4   id4 = *(const int4*)s_idx[slot];
        const float4 w4  = *(const float4*)s_w[slot];
#pragma unroll
        for (int c = 0; c < 4; ++c) {
            const int   id = (c == 0) ? id4.x : (c == 1) ? id4.y : (c == 2) ? id4.z : id4.w;
            const float w  = (c == 0) ? w4.x  : (c == 1) ? w4.y  : (c == 2) ? w4.z  : w4.w;
            const uint4 v = *(const uint4*)(basec + id);
            a0 += w * __uint_as_float(v.x << 16);
            a1 += w * __uint_as_float(v.x & 0xffff0000u);
            a2 += w * __uint_as_float(v.y << 16);
            a3 += w * __uint_as_float(v.y & 0xffff0000u);
            a4 += w * __uint_as_float(v.z << 16);
            a5 += w * __uint_as_float(v.z & 0xffff0000u);
            a6 += w * __uint_as_float(v.w << 16);
            a7 += w * __uint_as_float(v.w & 0xffff0000u);
        }
    }
    a0 += __shfl_xor(a0, 4); a1 += __shfl_xor(a1, 4);
    a2 += __shfl_xor(a2, 4); a3 += __shfl_xor(a3, 4);
    a4 += __shfl_xor(a4, 4); a5 += __shfl_xor(a5, 4);
    a6 += __shfl_xor(a6, 4); a7 += __shfl_xor(a7, 4);
    a0 += __shfl_xor(a0, 8); a1 += __shfl_xor(a1, 8);
    a2 += __shfl_xor(a2, 8); a3 += __shfl_xor(a3, 8);
    a4 += __shfl_xor(a4, 8); a5 += __shfl_xor(a5, 8);
    a6 += __shfl_xor(a6, 8); a7 += __shfl_xor(a7, 8);

    if (qtr == 0) {
        uint4 o;
        o.x = (unsigned)f2b(a0) | ((unsigned)f2b(a1) << 16);
        o.y = (unsigned)f2b(a2) | ((unsigned)f2b(a3) << 16);
        o.z = (unsigned)f2b(a4) | ((unsigned)f2b(a5) << 16);
        o.w = (unsigned)f2b(a6) | ((unsigned)f2b(a7) << 16);
        *(uint4*)&outpre[(size_t)q * 256 + h * 32 + c8 * 8] = o;
    }
}

// ---------------------------------------------------------------------------
extern "C" void kernel_launch(void* const* d_in, const int* in_sizes, int n_in,
                              void* d_out, int out_size, void* d_ws, size_t ws_size,
                              hipStream_t stream) {
    const float* query  = (const float*)d_in[0];
    const float* rp     = (const float*)d_in[1];
    const float* inflat = (const float*)d_in[2];
    const int*   sp     = (const int*)d_in[3];
    const int*   lsi    = (const int*)d_in[4];
    const float* W_off  = (const float*)d_in[5];
    const float* b_off  = (const float*)d_in[6];
    const float* W_attn = (const float*)d_in[7];
    const float* b_attn = (const float*)d_in[8];
    const float* W_val  = (const float*)d_in[9];
    const float* b_val  = (const float*)d_in[10];
    const float* W_out  = (const float*)d_in[11];
    const float* b_out  = (const float*)d_in[12];
    float* out = (float*)d_out;

    char* ws = (char*)d_ws;
    ushort_t* projb  = (ushort_t*)ws; ws += (size_t)QTOT * 256 * 2;
    ushort_t* offb   = (ushort_t*)ws; ws += (size_t)QTOT * 256 * 2;
    float*    logitf = (float*)ws;    ws += (size_t)QTOT * 128 * 4;
    ushort_t* outpre = (ushort_t*)ws; ws += (size_t)QTOT * 256 * 2;
    ushort_t* WvT    = (ushort_t*)ws; ws += 65536 * 2;
    ushort_t* WcT    = (ushort_t*)ws; ws += 98304 * 2;
    ushort_t* WoT    = (ushort_t*)ws; ws += 65536 * 2;
    float*    bcomb  = (float*)ws;    ws += 384 * 4;

    dim3 blk(256);

    prep<<<dim3(898), blk, 0, stream>>>(W_val, W_off, W_attn, W_out, b_off, b_attn,
                                        WvT, WcT, WoT, bcomb);

    gemm1<<<dim3(1920), blk, 0, stream>>>(inflat, query, WvT, WcT, b_val, bcomb,
                                          projb, offb, logitf);

    sample4<<<dim3(6120), blk, 0, stream>>>(rp, offb, logitf, projb, sp, lsi, outpre);

    gemm_o<<<dim3(768), blk, 0, stream>>>(outpre, WoT, b_out, out);
}

// Round 7
// 72.780 us; speedup vs baseline: 1.1373x; 1.1251x over previous
//
#include <hip/hip_runtime.h>

#define QTOT 12240
#define KD   256

typedef float f32x4 __attribute__((ext_vector_type(4)));
typedef short s16x8 __attribute__((ext_vector_type(8)));
typedef unsigned short ushort_t;

__device__ __forceinline__ unsigned short f2b(float x) {
    union { float f; unsigned u; } c; c.f = x;
    unsigned r = c.u + 0x7fffu + ((c.u >> 16) & 1u);
    return (unsigned short)(r >> 16);
}
// LDS row: 512B, XOR bits 4-6 of k-byte with row&7 (write & read sides)
__device__ __forceinline__ int swz(int row, int kb) { return row * 512 + (kb ^ ((row & 7) << 4)); }

// ---------------------------------------------------------------------------
// prep: weight transpose+bf16, combined off/attn bias
// ---------------------------------------------------------------------------
__global__ __launch_bounds__(256) void prep(
    const float* __restrict__ W_val, const float* __restrict__ W_off,
    const float* __restrict__ W_attn, const float* __restrict__ W_out,
    const float* __restrict__ b_off, const float* __restrict__ b_attn,
    ushort_t* __restrict__ WvT, ushort_t* __restrict__ WcT,
    ushort_t* __restrict__ WoT, float* __restrict__ bcomb)
{
    int id = blockIdx.x * 256 + threadIdx.x;
    if (id < 65536) { int n = id >> 8, k = id & 255; WvT[id] = f2b(W_val[k * 256 + n]); }
    else if (id < 163840) {
        int t = id - 65536; int n = t >> 8, k = t & 255;
        float v = (n < 256) ? W_off[k * 256 + n] : W_attn[k * 128 + (n - 256)];
        WcT[t] = f2b(v);
    } else if (id < 229376) {
        int t = id - 163840; int n = t >> 8, k = t & 255;
        WoT[t] = f2b(W_out[k * 256 + n]);
    } else if (id < 229760) {
        int t = id - 229376; bcomb[t] = (t < 256) ? b_off[t] : b_attn[t - 256];
    }
}

// ---------------------------------------------------------------------------
// gemm1: 766 blocks. b<383: value proj (A=inflat, N=256); else off/attn proj
// (A=query, N=384). BM=32, full-N per block -> every A byte read ONCE from
// HBM. A panel (32x256) f32->bf16 staged once into swizzled LDS (16KB),
// single barrier; then per 64-col chunk: B fragments direct from bf16 W^T
// in registers (L2-hot), 16 ds_read + 16 MFMA per wave, no further syncs.
// ---------------------------------------------------------------------------
__global__ __launch_bounds__(256) void gemm1(
    const float* __restrict__ inflat, const float* __restrict__ query,
    const ushort_t* __restrict__ WvT, const ushort_t* __restrict__ WcT,
    const float* __restrict__ b_val, const float* __restrict__ bcomb,
    ushort_t* __restrict__ projb, ushort_t* __restrict__ offb,
    float* __restrict__ logitf)
{
    __shared__ char As[16384];
    const int b = blockIdx.x;
    const bool isval = b < 383;
    const int bm = (isval ? b : b - 383) * 32;
    const float* A = isval ? inflat : query;
    const ushort_t* WT = isval ? WvT : WcT;
    const int nc = isval ? 4 : 6;

    const int tid = threadIdx.x, lane = tid & 63, wave = tid >> 6;
    const int lr = lane & 15, g8 = (lane >> 4) * 8;

    {   // stage A panel: 32 rows x 256 k, f32 -> bf16, once
        const int row = tid >> 3, c0 = (tid & 7) * 32;
        const int grow = bm + row;
        if (grow < QTOT) {
            const float4* src = (const float4*)(A + (size_t)grow * KD + c0);
#pragma unroll
            for (int j = 0; j < 4; ++j) {
                float4 f0 = src[j * 2 + 0], f1 = src[j * 2 + 1];
                s16x8 v;
                v[0] = f2b(f0.x); v[1] = f2b(f0.y); v[2] = f2b(f0.z); v[3] = f2b(f0.w);
                v[4] = f2b(f1.x); v[5] = f2b(f1.y); v[6] = f2b(f1.z); v[7] = f2b(f1.w);
                *(s16x8*)(As + swz(row, (c0 + j * 8) * 2)) = v;
            }
        } else {
            s16x8 z = (s16x8)0;
#pragma unroll
            for (int j = 0; j < 4; ++j)
                *(s16x8*)(As + swz(row, (c0 + j * 8) * 2)) = z;
        }
    }
    __syncthreads();

    const int rg = (lane >> 4) * 4;

    for (int c = 0; c < nc; ++c) {
        const int col = c * 64 + wave * 16 + lr;
        // B slice: fragment-exact from W^T (L2-hot)
        s16x8 bfr[8];
        {
            const ushort_t* bp = WT + (size_t)col * KD + g8;
#pragma unroll
            for (int kc = 0; kc < 8; ++kc) bfr[kc] = *(const s16x8*)(bp + kc * 32);
        }
        f32x4 acc[2];
        acc[0] = (f32x4)0.f; acc[1] = (f32x4)0.f;
#pragma unroll
        for (int kc = 0; kc < 8; ++kc) {
            const int kb = (kc * 32 + g8) * 2;
            s16x8 a0 = *(const s16x8*)(As + swz(lr,      kb));
            s16x8 a1 = *(const s16x8*)(As + swz(16 + lr, kb));
            acc[0] = __builtin_amdgcn_mfma_f32_16x16x32_bf16(a0, bfr[kc], acc[0], 0, 0, 0);
            acc[1] = __builtin_amdgcn_mfma_f32_16x16x32_bf16(a1, bfr[kc], acc[1], 0, 0, 0);
        }
        const float bb = isval ? b_val[col] : bcomb[col];
#pragma unroll
        for (int mf = 0; mf < 2; ++mf)
#pragma unroll
            for (int rr = 0; rr < 4; ++rr) {
                const int row = bm + mf * 16 + rg + rr;
                if (row >= QTOT) continue;
                const float v = acc[mf][rr] + bb;
                if (isval)          projb[(size_t)row * 256 + col] = f2b(v);
                else if (col < 256) offb [(size_t)row * 256 + col] = f2b(v);
                else                logitf[(size_t)row * 128 + col - 256] = v;
            }
    }
}

// ---------------------------------------------------------------------------
// gemm_o: LDS-free, barrier-free. 383 blocks, BM=32, full N=256 per block.
// A (bf16) fragments direct from global (block's 16KB A-slice is L1-hot
// across the 4 chunks); B from bf16 W^T (L2-hot).
// ---------------------------------------------------------------------------
__global__ __launch_bounds__(256) void gemm_o(
    const ushort_t* __restrict__ Ab, const ushort_t* __restrict__ WoT,
    const float* __restrict__ b_out, float* __restrict__ out)
{
    const int bm = blockIdx.x * 32;
    const int tid = threadIdx.x, lane = tid & 63, wave = tid >> 6;
    const int lr = lane & 15, g8 = (lane >> 4) * 8;
    const int rg = (lane >> 4) * 4;

    const ushort_t* ap0;
    const ushort_t* ap1;
    {
        int r0 = bm + lr;      if (r0 >= QTOT) r0 = QTOT - 1;
        int r1 = bm + 16 + lr; if (r1 >= QTOT) r1 = QTOT - 1;
        ap0 = Ab + (size_t)r0 * KD + g8;
        ap1 = Ab + (size_t)r1 * KD + g8;
    }

#pragma unroll
    for (int c = 0; c < 4; ++c) {
        const int col = c * 64 + wave * 16 + lr;
        s16x8 bfr[8];
        {
            const ushort_t* bp = WoT + (size_t)col * KD + g8;
#pragma unroll
            for (int kc = 0; kc < 8; ++kc) bfr[kc] = *(const s16x8*)(bp + kc * 32);
        }
        f32x4 acc[2];
        acc[0] = (f32x4)0.f; acc[1] = (f32x4)0.f;
#pragma unroll
        for (int kc = 0; kc < 8; ++kc) {
            s16x8 a0 = *(const s16x8*)(ap0 + kc * 32);
            s16x8 a1 = *(const s16x8*)(ap1 + kc * 32);
            acc[0] = __builtin_amdgcn_mfma_f32_16x16x32_bf16(a0, bfr[kc], acc[0], 0, 0, 0);
            acc[1] = __builtin_amdgcn_mfma_f32_16x16x32_bf16(a1, bfr[kc], acc[1], 0, 0, 0);
        }
        const float bb = b_out[col];
#pragma unroll
        for (int mf = 0; mf < 2; ++mf)
#pragma unroll
            for (int rr = 0; rr < 4; ++rr) {
                const int row = bm + mf * 16 + rg + rr;
                if (row < QTOT) out[(size_t)row * 256 + col] = acc[mf][rr] + bb;
            }
    }
}

// ---------------------------------------------------------------------------
// sample: unchanged (2 queries/block, dwordx4 gathers, XCD swizzle)
// ---------------------------------------------------------------------------
__global__ __launch_bounds__(256) void sample4(
    const float* __restrict__ rp, const ushort_t* __restrict__ offb,
    const float* __restrict__ logitf, const ushort_t* __restrict__ projb,
    const int* __restrict__ sp, const int* __restrict__ lsi,
    ushort_t* __restrict__ outpre)
{
    const int bid = blockIdx.x;
    const int qpair = (bid & 7) * 765 + (bid >> 3);     // 6120 = 8*765 bijective
    const int tid = threadIdx.x;
    const int qi = tid >> 7;
    const int q = qpair * 2 + qi;

    __shared__ int   s_idx[256][4];
    __shared__ float s_w[256][4];

    {
        const int t = tid & 127;
        const int l = (t >> 2) & 3;
        float logit = logitf[(size_t)q * 128 + t];
        float mx = logit;
#pragma unroll
        for (int d = 1; d < 16; d <<= 1) mx = fmaxf(mx, __shfl_xor(mx, d));
        float e = __expf(logit - mx);
        float s = e;
#pragma unroll
        for (int d = 1; d < 16; d <<= 1) s += __shfl_xor(s, d);
        const float aw = e / s;

        const unsigned opk = *(const unsigned*)&offb[(size_t)q * 256 + t * 2];
        const float ox = __uint_as_float(opk << 16);
        const float oy = __uint_as_float(opk & 0xffff0000u);

        const int Hl = sp[l * 2], Wl = sp[l * 2 + 1], st = lsi[l];
        const float rx = rp[((size_t)q * 4 + l) * 2 + 0];
        const float ry = rp[((size_t)q * 4 + l) * 2 + 1];

        const float x = rx * (float)Wl + ox - 0.5f;
        const float y = ry * (float)Hl + oy - 0.5f;
        const float xf = floorf(x), yf = floorf(y);
        const int x0 = (int)xf, y0 = (int)yf;
        const float lx = x - xf, ly = y - yf;

        const bool vx0 = (x0 >= 0) && (x0 < Wl);
        const bool vx1 = (x0 + 1 >= 0) && (x0 + 1 < Wl);
        const bool vy0 = (y0 >= 0) && (y0 < Hl);
        const bool vy1 = (y0 + 1 >= 0) && (y0 + 1 < Hl);

        s_w[tid][0] = (vx0 && vy0) ? aw * (1.f - ly) * (1.f - lx) : 0.f;
        s_w[tid][1] = (vx1 && vy0) ? aw * (1.f - ly) * lx         : 0.f;
        s_w[tid][2] = (vx0 && vy1) ? aw * ly * (1.f - lx)         : 0.f;
        s_w[tid][3] = (vx1 && vy1) ? aw * ly * lx                 : 0.f;
        s_idx[tid][0] = (vx0 && vy0) ? (st + y0 * Wl + x0) * 512           : 0;
        s_idx[tid][1] = (vx1 && vy0) ? (st + y0 * Wl + x0 + 1) * 512       : 0;
        s_idx[tid][2] = (vx0 && vy1) ? (st + (y0 + 1) * Wl + x0) * 512     : 0;
        s_idx[tid][3] = (vx1 && vy1) ? (st + (y0 + 1) * Wl + x0 + 1) * 512 : 0;
    }
    __syncthreads();

    const int tt = tid & 127;
    const int h = tt >> 4, qtr = (tt >> 2) & 3, c8 = tt & 3;
    const char* basec = (const char*)projb + (h * 32 + c8 * 8) * 2;

    float a0 = 0, a1 = 0, a2 = 0, a3 = 0, a4 = 0, a5 = 0, a6 = 0, a7 = 0;
#pragma unroll
    for (int p = 0; p < 4; ++p) {
        const int slot = qi * 128 + h * 16 + qtr * 4 + p;
        const int4   id4 = *(const int4*)s_idx[slot];
        const float4 w4  = *(const float4*)s_w[slot];
#pragma unroll
        for (int c = 0; c < 4; ++c) {
            const int   id = (c == 0) ? id4.x : (c == 1) ? id4.y : (c == 2) ? id4.z : id4.w;
            const float w  = (c == 0) ? w4.x  : (c == 1) ? w4.y  : (c == 2) ? w4.z  : w4.w;
            const uint4 v = *(const uint4*)(basec + id);
            a0 += w * __uint_as_float(v.x << 16);
            a1 += w * __uint_as_float(v.x & 0xffff0000u);
            a2 += w * __uint_as_float(v.y << 16);
            a3 += w * __uint_as_float(v.y & 0xffff0000u);
            a4 += w * __uint_as_float(v.z << 16);
            a5 += w * __uint_as_float(v.z & 0xffff0000u);
            a6 += w * __uint_as_float(v.w << 16);
            a7 += w * __uint_as_float(v.w & 0xffff0000u);
        }
    }
    a0 += __shfl_xor(a0, 4); a1 += __shfl_xor(a1, 4);
    a2 += __shfl_xor(a2, 4); a3 += __shfl_xor(a3, 4);
    a4 += __shfl_xor(a4, 4); a5 += __shfl_xor(a5, 4);
    a6 += __shfl_xor(a6, 4); a7 += __shfl_xor(a7, 4);
    a0 += __shfl_xor(a0, 8); a1 += __shfl_xor(a1, 8);
    a2 += __shfl_xor(a2, 8); a3 += __shfl_xor(a3, 8);
    a4 += __shfl_xor(a4, 8); a5 += __shfl_xor(a5, 8);
    a6 += __shfl_xor(a6, 8); a7 += __shfl_xor(a7, 8);

    if (qtr == 0) {
        uint4 o;
        o.x = (unsigned)f2b(a0) | ((unsigned)f2b(a1) << 16);
        o.y = (unsigned)f2b(a2) | ((unsigned)f2b(a3) << 16);
        o.z = (unsigned)f2b(a4) | ((unsigned)f2b(a5) << 16);
        o.w = (unsigned)f2b(a6) | ((unsigned)f2b(a7) << 16);
        *(uint4*)&outpre[(size_t)q * 256 + h * 32 + c8 * 8] = o;
    }
}

// ---------------------------------------------------------------------------
extern "C" void kernel_launch(void* const* d_in, const int* in_sizes, int n_in,
                              void* d_out, int out_size, void* d_ws, size_t ws_size,
                              hipStream_t stream) {
    const float* query  = (const float*)d_in[0];
    const float* rp     = (const float*)d_in[1];
    const float* inflat = (const float*)d_in[2];
    const int*   sp     = (const int*)d_in[3];
    const int*   lsi    = (const int*)d_in[4];
    const float* W_off  = (const float*)d_in[5];
    const float* b_off  = (const float*)d_in[6];
    const float* W_attn = (const float*)d_in[7];
    const float* b_attn = (const float*)d_in[8];
    const float* W_val  = (const float*)d_in[9];
    const float* b_val  = (const float*)d_in[10];
    const float* W_out  = (const float*)d_in[11];
    const float* b_out  = (const float*)d_in[12];
    float* out = (float*)d_out;

    char* ws = (char*)d_ws;
    ushort_t* projb  = (ushort_t*)ws; ws += (size_t)QTOT * 256 * 2;
    ushort_t* offb   = (ushort_t*)ws; ws += (size_t)QTOT * 256 * 2;
    float*    logitf = (float*)ws;    ws += (size_t)QTOT * 128 * 4;
    ushort_t* outpre = (ushort_t*)ws; ws += (size_t)QTOT * 256 * 2;
    ushort_t* WvT    = (ushort_t*)ws; ws += 65536 * 2;
    ushort_t* WcT    = (ushort_t*)ws; ws += 98304 * 2;
    ushort_t* WoT    = (ushort_t*)ws; ws += 65536 * 2;
    float*    bcomb  = (float*)ws;    ws += 384 * 4;

    dim3 blk(256);

    prep<<<dim3(898), blk, 0, stream>>>(W_val, W_off, W_attn, W_out, b_off, b_attn,
                                        WvT, WcT, WoT, bcomb);

    gemm1<<<dim3(766), blk, 0, stream>>>(inflat, query, WvT, WcT, b_val, bcomb,
                                         projb, offb, logitf);

    sample4<<<dim3(6120), blk, 0, stream>>>(rp, offb, logitf, projb, sp, lsi, outpre);

    gemm_o<<<dim3(383), blk, 0, stream>>>(outpre, WoT, b_out, out);
}